// Round 2
// baseline (456.150 us; speedup 1.0000x reference)
//
#include <hip/hip_runtime.h>
#include <hip/hip_bf16.h>

#define NL 2
// B=32, K=64, D=256, LS=128, rows = B*K = 2048

using bf16 = __hip_bfloat16;

__device__ __forceinline__ float bfu(unsigned short u) { return __uint_as_float(((unsigned)u) << 16); }

// exact gelu (matches jax approximate=False)
__device__ __forceinline__ float gelu_e(float x) {
  return 0.5f * x * (1.0f + erff(x * 0.7071067811865475f));
}

// dtype-adaptive input load: fl=1 -> bf16 halfwords, fl=0 -> fp32
__device__ __forceinline__ float load_f(const void* p, int i, int fl) {
  if (fl) return bfu(((const unsigned short*)p)[i]);
  return ((const float*)p)[i];
}

// ---------------------------------------------------------------------------
// detect: view first 256 halfwords of X as bf16; fp32 data shows insane values
// ---------------------------------------------------------------------------
__global__ __launch_bounds__(256) void detect_kernel(const void* __restrict__ X, int* __restrict__ flag) {
  __shared__ int bad;
  if (threadIdx.x == 0) bad = 0;
  __syncthreads();
  const unsigned short h = ((const unsigned short*)X)[threadIdx.x];
  const float v = bfu(h);
  if (!(fabsf(v) < 1e6f)) atomicOr(&bad, 1);   // catches Inf/NaN too
  __syncthreads();
  if (threadIdx.x == 0) *flag = bad ? 0 : 1;    // 1 = inputs are bf16
}

// ---------------------------------------------------------------------------
// prep: inputs -> fp32 in ws (dtype-adaptive)
//   wf  [NL][256 d][1024 n]: n<256 k_w | q_w*scale | Wa+Wb | Wb
//   w3  [NL*3][256 d][256 e]: rv_w2^T, mlp_w1^T, mlp_w2^T
//   wh  : projT [256][128], muT [128][128], spT [128][128]
//   bc  : rb1|rb2|lng|lnb|mb1|mb2 (NL*256 each), pb|mub|spb (128 each)
// ---------------------------------------------------------------------------
__global__ __launch_bounds__(256) void prep_kernel(
    const void* __restrict__ X, const void* __restrict__ kw, const void* __restrict__ qw,
    const void* __restrict__ rw1, const void* __restrict__ rw2, const void* __restrict__ mw1,
    const void* __restrict__ mw2, const void* __restrict__ pw, const void* __restrict__ muw,
    const void* __restrict__ spw,
    const void* __restrict__ rb1, const void* __restrict__ rb2, const void* __restrict__ lng,
    const void* __restrict__ lnb, const void* __restrict__ mb1, const void* __restrict__ mb2,
    const void* __restrict__ pb, const void* __restrict__ mub, const void* __restrict__ spb,
    const int* __restrict__ flag,
    float* __restrict__ x, float* __restrict__ wf, float* __restrict__ w3,
    float* __restrict__ wh, float* __restrict__ bc)
{
  const int fl = *flag;
  int idx = blockIdx.x * 256 + threadIdx.x;
  if (idx < NL * 262144) {
    int l = idx >> 18, rem = idx & 262143;
    int d = rem >> 10, n = rem & 1023;
    int seg = n >> 8, e = n & 255;
    float v;
    if (seg == 0)      v = load_f(kw, (l*256 + e)*256 + d, fl);
    else if (seg == 1) v = load_f(qw, (l*256 + e)*256 + d, fl) * 0.0625f;  // D^-0.5
    else {
      const int rbase = (l*256 + e)*512;
      float wb = load_f(rw1, rbase + 256 + d, fl);
      v = (seg == 2) ? (load_f(rw1, rbase + d, fl) + wb) : wb;
    }
    wf[idx] = v;
    return;
  }
  idx -= NL * 262144;
  if (idx < NL * 3 * 65536) {
    int l3 = idx >> 16, rem = idx & 65535;
    int d = rem >> 8, e = rem & 255;
    int l = l3 / 3, m = l3 % 3;
    const void* src = (m == 0) ? rw2 : (m == 1) ? mw1 : mw2;
    w3[idx] = load_f(src, (l*256 + e)*256 + d, fl);
    return;
  }
  idx -= NL * 3 * 65536;
  if (idx < 65536) {
    if (idx < 32768) {
      int d = idx >> 7, l = idx & 127;
      wh[idx] = load_f(pw, l*256 + d, fl);
    } else if (idx < 49152) {
      int rem = idx - 32768, c = rem >> 7, l = rem & 127;
      wh[idx] = load_f(muw, l*128 + c, fl);
    } else {
      int rem = idx - 49152, c = rem >> 7, l = rem & 127;
      wh[idx] = load_f(spw, l*128 + c, fl);
    }
    return;
  }
  idx -= 65536;
  if (idx < 524288) {
    x[idx] = load_f(X, idx, fl);
    return;
  }
  idx -= 524288;
  if (idx < 3456) {
    const void* src; int off;
    if (idx < 512)       { src = rb1; off = idx; }
    else if (idx < 1024) { src = rb2; off = idx - 512; }
    else if (idx < 1536) { src = lng; off = idx - 1024; }
    else if (idx < 2048) { src = lnb; off = idx - 1536; }
    else if (idx < 2560) { src = mb1; off = idx - 2048; }
    else if (idx < 3072) { src = mb2; off = idx - 2560; }
    else if (idx < 3200) { src = pb;  off = idx - 3072; }
    else if (idx < 3328) { src = mub; off = idx - 3200; }
    else                 { src = spb; off = idx - 3328; }
    bc[idx] = load_f(src, off, fl);
  }
}

// ---------------------------------------------------------------------------
// k1: kqpq[row][1024] = x[row][:] @ wf + bias   (k | q*scale | P(+rb1) | Q)
// 8 rows/block, thread t owns cols 4t..4t+3 (float4-coalesced weight loads)
// ---------------------------------------------------------------------------
__global__ __launch_bounds__(256) void k1_kqpq(
    const float* __restrict__ x, const float* __restrict__ wf_all,
    const float* __restrict__ bc, float* __restrict__ kqpq, int l)
{
  __shared__ float xs[8][256];
  const int t = threadIdx.x;
  const int row0 = blockIdx.x * 8;
  for (int idx = t; idx < 8*256; idx += 256)
    xs[idx >> 8][idx & 255] = x[row0*256 + idx];
  __syncthreads();

  const float* w = wf_all + l*262144;
  const float* rb1c = bc + l*256;
  const int n0 = t * 4;
  float4 bv = make_float4(0.f, 0.f, 0.f, 0.f);
  if ((n0 >> 8) == 2) {     // P segment gets rb1
    const int e = n0 & 255;
    bv.x = rb1c[e]; bv.y = rb1c[e+1]; bv.z = rb1c[e+2]; bv.w = rb1c[e+3];
  }
  float4 acc[8];
  #pragma unroll
  for (int r = 0; r < 8; ++r) acc[r] = bv;

  for (int d0 = 0; d0 < 256; d0 += 4) {
    float4 xv[8];
    #pragma unroll
    for (int r = 0; r < 8; ++r) xv[r] = *(const float4*)&xs[r][d0];
    #pragma unroll
    for (int dd = 0; dd < 4; ++dd) {
      const float4 wv = *(const float4*)&w[(d0 + dd)*1024 + n0];
      #pragma unroll
      for (int r = 0; r < 8; ++r) {
        const float xr = (dd == 0) ? xv[r].x : (dd == 1) ? xv[r].y : (dd == 2) ? xv[r].z : xv[r].w;
        acc[r].x = fmaf(xr, wv.x, acc[r].x);
        acc[r].y = fmaf(xr, wv.y, acc[r].y);
        acc[r].z = fmaf(xr, wv.z, acc[r].z);
        acc[r].w = fmaf(xr, wv.w, acc[r].w);
      }
    }
  }
  #pragma unroll
  for (int r = 0; r < 8; ++r)
    *(float4*)&kqpq[(row0 + r)*1024 + n0] = acc[r];
}

// ---------------------------------------------------------------------------
// k23: per (b, 4 i's): scores -> wave64 softmax -> g = sum_j a_ij gelu(P_i - Q_j)
// q staged in LDS (broadcast reads); k rows read fp32 from L2
// ---------------------------------------------------------------------------
__global__ __launch_bounds__(256) void k23_attn_agg(
    const float* __restrict__ kqpq, float* __restrict__ g)
{
  __shared__ float qs[4][256];
  __shared__ float aa[4][64];
  const int t = threadIdx.x;
  const int b = (int)blockIdx.x >> 4;
  const int i0 = ((int)blockIdx.x & 15) * 4;
  const int base = b << 6;

  for (int idx = t; idx < 4*256; idx += 256) {
    const int r = idx >> 8, d = idx & 255;
    qs[r][d] = kqpq[(base + i0 + r)*1024 + 256 + d];
  }
  __syncthreads();
  {
    const int il = t >> 6, j = t & 63;   // one wave per row il
    const float* krow = kqpq + (base + j)*1024;
    float s = 0.f;
    for (int d0 = 0; d0 < 256; d0 += 4) {
      const float4 kv = *(const float4*)&krow[d0];
      const float4 qv = *(const float4*)&qs[il][d0];
      s = fmaf(qv.x, kv.x, s);
      s = fmaf(qv.y, kv.y, s);
      s = fmaf(qv.z, kv.z, s);
      s = fmaf(qv.w, kv.w, s);
    }
    float m = s;
    #pragma unroll
    for (int off = 32; off; off >>= 1) m = fmaxf(m, __shfl_xor(m, off, 64));
    const float e = __expf(s - m);
    float ssum = e;
    #pragma unroll
    for (int off = 32; off; off >>= 1) ssum += __shfl_xor(ssum, off, 64);
    aa[il][j] = e / ssum;
  }
  __syncthreads();

  float p[4], acc[4];
  #pragma unroll
  for (int r = 0; r < 4; ++r) {
    p[r] = kqpq[(base + i0 + r)*1024 + 512 + t];   // P
    acc[r] = 0.f;
  }
  for (int j = 0; j < 64; ++j) {
    const float qv = kqpq[(base + j)*1024 + 768 + t];  // Q
    #pragma unroll
    for (int r = 0; r < 4; ++r)
      acc[r] = fmaf(aa[r][j], gelu_e(p[r] - qv), acc[r]);
  }
  #pragma unroll
  for (int r = 0; r < 4; ++r)
    g[(base + i0 + r)*256 + t] = acc[r];
}

// ---------------------------------------------------------------------------
// k4: agg = g@rw2^T+rb2 ; h=LN(x+agg) ; x += mlp2(gelu(mlp1(h)))   (in-place)
// ---------------------------------------------------------------------------
__device__ __forceinline__ float getc(const float4 v, int i) {
  return (i == 0) ? v.x : (i == 1) ? v.y : (i == 2) ? v.z : v.w;
}

__device__ __forceinline__ void tile_gemm(
    const float* src, const float* __restrict__ wT,
    float b0, float b1, int rs, int e0, float* a0, float* a1)
{
  #pragma unroll
  for (int r = 0; r < 8; ++r) { a0[r] = b0; a1[r] = b1; }
  for (int d0 = 0; d0 < 256; d0 += 4) {
    float4 sv[8];
    #pragma unroll
    for (int r = 0; r < 8; ++r) sv[r] = *(const float4*)&src[(rs*8 + r)*256 + d0];
    #pragma unroll
    for (int dd = 0; dd < 4; ++dd) {
      const float2 wv = *(const float2*)&wT[(d0 + dd)*256 + e0];
      #pragma unroll
      for (int r = 0; r < 8; ++r) {
        const float s = getc(sv[r], dd);
        a0[r] = fmaf(s, wv.x, a0[r]);
        a1[r] = fmaf(s, wv.y, a1[r]);
      }
    }
  }
}

__global__ __launch_bounds__(256) void k4_mix(
    const float* __restrict__ g, const float* __restrict__ w3,
    const float* __restrict__ bc, float* __restrict__ x, int l)
{
  __shared__ float xt[16*256];
  __shared__ float bufA[16*256];
  __shared__ float bufB[16*256];
  __shared__ float mv[16][2];
  const int t = threadIdx.x;
  const int row0 = blockIdx.x * 16;
  for (int idx = t; idx < 16*256; idx += 256) {
    xt[idx]   = x[row0*256 + idx];
    bufA[idx] = g[row0*256 + idx];
  }
  __syncthreads();
  const int cg = t & 127, rs = t >> 7;
  const int e0 = cg * 2;
  const float* wl = w3 + l*3*65536;
  const float* rb2c = bc + 512  + l*256;
  const float* lngc = bc + 1024 + l*256;
  const float* lnbc = bc + 1536 + l*256;
  const float* mb1c = bc + 2048 + l*256;
  const float* mb2c = bc + 2560 + l*256;
  float a0[8], a1[8];

  tile_gemm(bufA, wl, rb2c[e0], rb2c[e0+1], rs, e0, a0, a1);
  #pragma unroll
  for (int r = 0; r < 8; ++r) {
    const int rr = rs*8 + r;
    bufB[rr*256 + e0]     = xt[rr*256 + e0]     + a0[r];
    bufB[rr*256 + e0 + 1] = xt[rr*256 + e0 + 1] + a1[r];
  }
  __syncthreads();
  {
    const int row = t >> 4, part = t & 15;
    float s = 0.f, s2 = 0.f;
    for (int kk = part; kk < 256; kk += 16) {
      const float v = bufB[row*256 + kk];
      s += v; s2 = fmaf(v, v, s2);
    }
    #pragma unroll
    for (int off = 8; off; off >>= 1) {
      s  += __shfl_xor(s, off, 16);
      s2 += __shfl_xor(s2, off, 16);
    }
    if (part == 0) {
      const float mu = s * (1.f/256.f);
      mv[row][0] = mu;
      mv[row][1] = rsqrtf(fmaf(-mu, mu, s2 * (1.f/256.f)) + 1e-5f);
    }
  }
  __syncthreads();
  {
    const float g0 = lngc[e0], g1 = lngc[e0+1];
    const float c0 = lnbc[e0], c1 = lnbc[e0+1];
    #pragma unroll
    for (int r = 0; r < 8; ++r) {
      const int rr = rs*8 + r;
      const float m = mv[rr][0], iv = mv[rr][1];
      bufB[rr*256 + e0]     = (bufB[rr*256 + e0]     - m) * iv * g0 + c0;
      bufB[rr*256 + e0 + 1] = (bufB[rr*256 + e0 + 1] - m) * iv * g1 + c1;
    }
  }
  __syncthreads();
  tile_gemm(bufB, wl + 65536, mb1c[e0], mb1c[e0+1], rs, e0, a0, a1);
  #pragma unroll
  for (int r = 0; r < 8; ++r) {
    const int rr = rs*8 + r;
    bufA[rr*256 + e0]     = gelu_e(a0[r]);
    bufA[rr*256 + e0 + 1] = gelu_e(a1[r]);
  }
  __syncthreads();
  tile_gemm(bufA, wl + 2*65536, mb2c[e0], mb2c[e0+1], rs, e0, a0, a1);
  #pragma unroll
  for (int r = 0; r < 8; ++r) {
    const int rr = rs*8 + r;
    float2 o;
    o.x = xt[rr*256 + e0]     + a0[r];
    o.y = xt[rr*256 + e0 + 1] + a1[r];
    *(float2*)&x[(row0 + rr)*256 + e0] = o;
  }
}

// ---------------------------------------------------------------------------
// k5: s=sum_K x ; h=gelu(s@projT+pb) ; mu=h@muT+mb ; scale=softplus(h@spT+sb)
// one block per batch; output dtype per flag
// ---------------------------------------------------------------------------
__global__ __launch_bounds__(256) void k5_head(
    const float* __restrict__ x, const float* __restrict__ wh,
    const float* __restrict__ bc, const int* __restrict__ flag,
    void* __restrict__ out)
{
  __shared__ float ss[256];
  __shared__ float hh[128];
  const int b = blockIdx.x, t = threadIdx.x;
  const int fl = *flag;
  float s = 0.f;
  for (int i = 0; i < 64; ++i) s += x[((b << 6) + i)*256 + t];
  ss[t] = s;
  __syncthreads();
  if (t < 128) {
    float acc = bc[3072 + t];
    const float* projT = wh;
    for (int d = 0; d < 256; ++d) acc = fmaf(ss[d], projT[d*128 + t], acc);
    hh[t] = gelu_e(acc);
  }
  __syncthreads();
  float v; int oidx;
  if (t < 128) {
    float acc = bc[3200 + t];
    const float* muT = wh + 32768;
    for (int c = 0; c < 128; ++c) acc = fmaf(hh[c], muT[c*128 + t], acc);
    v = acc; oidx = b*128 + t;
  } else {
    const int u = t - 128;
    float acc = bc[3328 + u];
    const float* spT = wh + 49152;
    for (int c = 0; c < 128; ++c) acc = fmaf(hh[c], spT[c*128 + u], acc);
    v = (acc > 20.f) ? acc : log1pf(__expf(acc));
    oidx = 4096 + b*128 + u;
  }
  if (fl) ((bf16*)out)[oidx] = __float2bfloat16(v);
  else    ((float*)out)[oidx] = v;
}

// ---------------------------------------------------------------------------
extern "C" void kernel_launch(void* const* d_in, const int* in_sizes, int n_in,
                              void* d_out, int out_size, void* d_ws, size_t ws_size,
                              hipStream_t stream)
{
  (void)in_sizes; (void)n_in; (void)out_size; (void)ws_size;
  float* ws    = (float*)d_ws;
  int*   flag  = (int*)ws;                // [16 floats reserved]
  float* x     = ws + 16;                 // 524288
  float* kqpq  = x + 524288;              // 2097152
  float* g     = kqpq + 2097152;          // 524288
  float* wf    = g + 524288;              // NL*262144 = 524288
  float* w3    = wf + 524288;             // NL*3*65536 = 393216
  float* wh    = w3 + 393216;             // 65536
  float* bc    = wh + 65536;              // 3456
  // total ws use ~16.5 MB

  detect_kernel<<<dim3(1), dim3(256), 0, stream>>>(d_in[0], flag);
  prep_kernel<<<dim3(5902), dim3(256), 0, stream>>>(
      d_in[0], d_in[1], d_in[2], d_in[3], d_in[5], d_in[9], d_in[11],
      d_in[13], d_in[15], d_in[17],
      d_in[4], d_in[6], d_in[7], d_in[8], d_in[10], d_in[12],
      d_in[14], d_in[16], d_in[18],
      flag, x, wf, w3, wh, bc);
  for (int l = 0; l < NL; ++l) {
    k1_kqpq<<<dim3(256), dim3(256), 0, stream>>>(x, wf, bc, kqpq, l);
    k23_attn_agg<<<dim3(512), dim3(256), 0, stream>>>(kqpq, g);
    k4_mix<<<dim3(128), dim3(256), 0, stream>>>(g, w3, bc, x, l);
  }
  k5_head<<<dim3(32), dim3(256), 0, stream>>>(x, wh, bc, flag, (void*)d_out);
}

// Round 3
// 318.292 us; speedup vs baseline: 1.4331x; 1.4331x over previous
//
#include <hip/hip_runtime.h>
#include <hip/hip_bf16.h>

#define NL 2
// B=32, K=64, D=256, LS=128, rows = B*K = 2048

using bf16 = __hip_bfloat16;

__device__ __forceinline__ float bfu(unsigned short u) { return __uint_as_float(((unsigned)u) << 16); }

__device__ __forceinline__ unsigned short bfr(float v) {   // RNE fp32->bf16 bits
  unsigned u = __float_as_uint(v);
  u += 0x7FFFu + ((u >> 16) & 1u);
  return (unsigned short)(u >> 16);
}

// tanh-form gelu, overflow-safe, hw exp (|err| vs exact erf-gelu ~1e-3)
__device__ __forceinline__ float gelu_t(float x) {
  float x2 = x * x;
  float z  = x * fmaf(0.0356774081f, x2, 0.7978845608f);
  float az = fabsf(z);
  float e  = __expf(-2.0f * az);
  float th = (1.0f - e) * __builtin_amdgcn_rcpf(1.0f + e);
  th = (z >= 0.f) ? th : -th;
  return 0.5f * x * (1.0f + th);
}

// exact gelu for the low-volume spots (k4 MLP, k5 head)
__device__ __forceinline__ float gelu_e(float x) {
  return 0.5f * x * (1.0f + erff(x * 0.7071067811865475f));
}

// dtype-adaptive input load: fl=1 -> bf16 halfwords, fl=0 -> fp32
__device__ __forceinline__ float load_f(const void* p, int i, int fl) {
  if (fl) return bfu(((const unsigned short*)p)[i]);
  return ((const float*)p)[i];
}

// ---------------------------------------------------------------------------
// detect: view first 256 halfwords of X as bf16; fp32 data shows insane values
// ---------------------------------------------------------------------------
__global__ __launch_bounds__(256) void detect_kernel(const void* __restrict__ X, int* __restrict__ flag) {
  __shared__ int bad;
  if (threadIdx.x == 0) bad = 0;
  __syncthreads();
  const unsigned short h = ((const unsigned short*)X)[threadIdx.x];
  const float v = bfu(h);
  if (!(fabsf(v) < 1e6f)) atomicOr(&bad, 1);
  __syncthreads();
  if (threadIdx.x == 0) *flag = bad ? 0 : 1;    // 1 = inputs are bf16
}

// ---------------------------------------------------------------------------
// prep: inputs -> fp32 in ws (dtype-adaptive)
//   wf  [NL][256 d][1024 n]: n<256 k_w | q_w*scale | Wa+Wb | Wb
//   w3  [NL*3][256 d][256 e]: rv_w2^T, mlp_w1^T, mlp_w2^T
//   wh  : projT [256][128], muT [128][128], spT [128][128]
//   bc  : rb1|rb2|lng|lnb|mb1|mb2 (NL*256 each), pb|mub|spb (128 each)
// ---------------------------------------------------------------------------
__global__ __launch_bounds__(256) void prep_kernel(
    const void* __restrict__ X, const void* __restrict__ kw, const void* __restrict__ qw,
    const void* __restrict__ rw1, const void* __restrict__ rw2, const void* __restrict__ mw1,
    const void* __restrict__ mw2, const void* __restrict__ pw, const void* __restrict__ muw,
    const void* __restrict__ spw,
    const void* __restrict__ rb1, const void* __restrict__ rb2, const void* __restrict__ lng,
    const void* __restrict__ lnb, const void* __restrict__ mb1, const void* __restrict__ mb2,
    const void* __restrict__ pb, const void* __restrict__ mub, const void* __restrict__ spb,
    const int* __restrict__ flag,
    float* __restrict__ x, float* __restrict__ wf, float* __restrict__ w3,
    float* __restrict__ wh, float* __restrict__ bc)
{
  const int fl = *flag;
  int idx = blockIdx.x * 256 + threadIdx.x;
  if (idx < NL * 262144) {
    int l = idx >> 18, rem = idx & 262143;
    int d = rem >> 10, n = rem & 1023;
    int seg = n >> 8, e = n & 255;
    float v;
    if (seg == 0)      v = load_f(kw, (l*256 + e)*256 + d, fl);
    else if (seg == 1) v = load_f(qw, (l*256 + e)*256 + d, fl) * 0.0625f;  // D^-0.5
    else {
      const int rbase = (l*256 + e)*512;
      float wb = load_f(rw1, rbase + 256 + d, fl);
      v = (seg == 2) ? (load_f(rw1, rbase + d, fl) + wb) : wb;
    }
    wf[idx] = v;
    return;
  }
  idx -= NL * 262144;
  if (idx < NL * 3 * 65536) {
    int l3 = idx >> 16, rem = idx & 65535;
    int d = rem >> 8, e = rem & 255;
    int l = l3 / 3, m = l3 % 3;
    const void* src = (m == 0) ? rw2 : (m == 1) ? mw1 : mw2;
    w3[idx] = load_f(src, (l*256 + e)*256 + d, fl);
    return;
  }
  idx -= NL * 3 * 65536;
  if (idx < 65536) {
    if (idx < 32768) {
      int d = idx >> 7, l = idx & 127;
      wh[idx] = load_f(pw, l*256 + d, fl);
    } else if (idx < 49152) {
      int rem = idx - 32768, c = rem >> 7, l = rem & 127;
      wh[idx] = load_f(muw, l*128 + c, fl);
    } else {
      int rem = idx - 49152, c = rem >> 7, l = rem & 127;
      wh[idx] = load_f(spw, l*128 + c, fl);
    }
    return;
  }
  idx -= 65536;
  if (idx < 524288) {
    x[idx] = load_f(X, idx, fl);
    return;
  }
  idx -= 524288;
  if (idx < 3456) {
    const void* src; int off;
    if (idx < 512)       { src = rb1; off = idx; }
    else if (idx < 1024) { src = rb2; off = idx - 512; }
    else if (idx < 1536) { src = lng; off = idx - 1024; }
    else if (idx < 2048) { src = lnb; off = idx - 1536; }
    else if (idx < 2560) { src = mb1; off = idx - 2048; }
    else if (idx < 3072) { src = mb2; off = idx - 2560; }
    else if (idx < 3200) { src = pb;  off = idx - 3072; }
    else if (idx < 3328) { src = mub; off = idx - 3200; }
    else                 { src = spb; off = idx - 3328; }
    bc[idx] = load_f(src, off, fl);
  }
}

// ---------------------------------------------------------------------------
// k1: kqpq[2048][1024] = x[2048][256] @ wf + bias  (k | q*scale | P(+rb1) | Q)
// 64x128 tile per block, 256 blocks. X-tile in LDS (broadcast reads).
// thread (tr,tc): 8 rows x 4 cols, float4 weight loads.
// ---------------------------------------------------------------------------
__global__ __launch_bounds__(256, 2) void k1_kqpq(
    const float* __restrict__ x, const float* __restrict__ wf_all,
    const float* __restrict__ bc, float* __restrict__ kqpq, int l)
{
  __shared__ float xs[64*256];   // 64 KB
  const int t = threadIdx.x;
  const int br  = (int)blockIdx.x >> 3;    // 32 row-blocks of 64 rows
  const int bcn = (int)blockIdx.x & 7;     // 8 col-blocks of 128 cols
  const int row0 = br * 64;
  const float* xsrc = x + row0*256;
  for (int i = t; i < 4096; i += 256)
    *(float4*)&xs[i*4] = *(const float4*)&xsrc[i*4];
  __syncthreads();

  const int tr = t >> 5, tc = t & 31;
  const int n0 = bcn*128 + tc*4;
  const float* w = wf_all + l*262144;
  float4 bv = make_float4(0.f, 0.f, 0.f, 0.f);
  if (n0 >= 512 && n0 < 768) {   // P segment gets rb1 (wave-uniform branch)
    const float* rb1c = bc + l*256 + (n0 - 512);
    bv = make_float4(rb1c[0], rb1c[1], rb1c[2], rb1c[3]);
  }
  float4 acc[8];
  #pragma unroll
  for (int r = 0; r < 8; ++r) acc[r] = bv;

  for (int d0 = 0; d0 < 256; d0 += 4) {
    float4 wv[4];
    #pragma unroll
    for (int dd = 0; dd < 4; ++dd) wv[dd] = *(const float4*)&w[(d0 + dd)*1024 + n0];
    #pragma unroll
    for (int r = 0; r < 8; ++r) {
      const float4 xv = *(const float4*)&xs[(tr*8 + r)*256 + d0];
      acc[r].x = fmaf(xv.x, wv[0].x, acc[r].x);
      acc[r].y = fmaf(xv.x, wv[0].y, acc[r].y);
      acc[r].z = fmaf(xv.x, wv[0].z, acc[r].z);
      acc[r].w = fmaf(xv.x, wv[0].w, acc[r].w);
      acc[r].x = fmaf(xv.y, wv[1].x, acc[r].x);
      acc[r].y = fmaf(xv.y, wv[1].y, acc[r].y);
      acc[r].z = fmaf(xv.y, wv[1].z, acc[r].z);
      acc[r].w = fmaf(xv.y, wv[1].w, acc[r].w);
      acc[r].x = fmaf(xv.z, wv[2].x, acc[r].x);
      acc[r].y = fmaf(xv.z, wv[2].y, acc[r].y);
      acc[r].z = fmaf(xv.z, wv[2].z, acc[r].z);
      acc[r].w = fmaf(xv.z, wv[2].w, acc[r].w);
      acc[r].x = fmaf(xv.w, wv[3].x, acc[r].x);
      acc[r].y = fmaf(xv.w, wv[3].y, acc[r].y);
      acc[r].z = fmaf(xv.w, wv[3].z, acc[r].z);
      acc[r].w = fmaf(xv.w, wv[3].w, acc[r].w);
    }
  }
  #pragma unroll
  for (int r = 0; r < 8; ++r)
    *(float4*)&kqpq[(row0 + tr*8 + r)*1024 + n0] = acc[r];
}

// ---------------------------------------------------------------------------
// k23: block = (b, i-pair). scores (4 waves, k bf16 in LDS) -> softmax ->
//      g = sum_j a_ij gelu(P_i - Q_j)  (256 threads = d, 2 rows each)
// 1024 blocks, ~37 KB LDS -> 4 blocks/CU
// ---------------------------------------------------------------------------
#define KS_STRIDE 268
__global__ __launch_bounds__(256) void k23_attn_agg(
    const float* __restrict__ kqpq, float* __restrict__ g)
{
  __shared__ unsigned short ks[64*KS_STRIDE];
  __shared__ float qrow[2][256];
  __shared__ float sc[2][64];
  __shared__ float aa[2][64];
  const int t = threadIdx.x;
  const int b = (int)blockIdx.x >> 5;
  const int ip = (int)blockIdx.x & 31;
  const int base = b << 6, i0 = ip*2;

  // stage k (bf16) and q rows
  for (int i = t; i < 4096; i += 256) {          // 64 j x 64 float4-chunks
    const int j = i >> 6, d4 = (i & 63)*4;
    const float4 kv = *(const float4*)&kqpq[(base + j)*1024 + d4];
    ushort4 o;
    o.x = bfr(kv.x); o.y = bfr(kv.y); o.z = bfr(kv.z); o.w = bfr(kv.w);
    *(ushort4*)&ks[j*KS_STRIDE + d4] = o;
  }
  for (int i = t; i < 512; i += 256)
    qrow[i >> 8][i & 255] = kqpq[(base + i0 + (i >> 8))*1024 + 256 + (i & 255)];
  __syncthreads();

  // scores: wave w -> (row = w&1, j-half = w>>1); lane = (dh<<5)|jl
  {
    const int w = t >> 6, lane = t & 63;
    const int row = w & 1, jh = w >> 1;
    const int jl = lane & 31, dh = lane >> 5;
    const int j = jh*32 + jl;
    const unsigned short* kp = &ks[j*KS_STRIDE + dh*128];
    const float* qp = &qrow[row][dh*128];
    float s = 0.f;
    for (int d0 = 0; d0 < 128; d0 += 4) {
      const ushort4 kv = *(const ushort4*)&kp[d0];
      const float4  qv = *(const float4*)&qp[d0];
      s = fmaf(qv.x, bfu(kv.x), s);
      s = fmaf(qv.y, bfu(kv.y), s);
      s = fmaf(qv.z, bfu(kv.z), s);
      s = fmaf(qv.w, bfu(kv.w), s);
    }
    s += __shfl_xor(s, 32, 64);
    if (dh == 0) sc[row][j] = s;
  }
  __syncthreads();
  if (t < 128) {
    const int row = t >> 6, j = t & 63;
    float s = sc[row][j];
    float m = s;
    #pragma unroll
    for (int off = 32; off; off >>= 1) m = fmaxf(m, __shfl_xor(m, off, 64));
    const float e = __expf(s - m);
    float ssum = e;
    #pragma unroll
    for (int off = 32; off; off >>= 1) ssum += __shfl_xor(ssum, off, 64);
    aa[row][j] = e / ssum;
  }
  __syncthreads();

  // aggregation: thread t = dim d, 2 rows
  const int d = t;
  const float p0 = kqpq[(base + i0    )*1024 + 512 + d];
  const float p1 = kqpq[(base + i0 + 1)*1024 + 512 + d];
  float a0 = 0.f, a1 = 0.f;
  for (int j = 0; j < 64; ++j) {
    const float qv = kqpq[(base + j)*1024 + 768 + d];
    const float w0 = aa[0][j], w1 = aa[1][j];
    a0 = fmaf(w0, gelu_t(p0 - qv), a0);
    a1 = fmaf(w1, gelu_t(p1 - qv), a1);
  }
  g[(base + i0    )*256 + d] = a0;
  g[(base + i0 + 1)*256 + d] = a1;
}

// ---------------------------------------------------------------------------
// k4: agg = g@rw2^T+rb2 ; h=LN(x+agg) ; x += mlp2(gelu(mlp1(h)))   (in-place)
// 8 rows/block -> 256 blocks; thread = (rs: 4-row half, cg -> cols 2cg,2cg+1)
// ---------------------------------------------------------------------------
__device__ __forceinline__ float getc(const float4 v, int i) {
  return (i == 0) ? v.x : (i == 1) ? v.y : (i == 2) ? v.z : v.w;
}

__device__ __forceinline__ void tile_gemm4(
    const float* src, const float* __restrict__ wT,
    float b0, float b1, int r0, int e0, float* a0, float* a1)
{
  #pragma unroll
  for (int r = 0; r < 4; ++r) { a0[r] = b0; a1[r] = b1; }
  for (int d0 = 0; d0 < 256; d0 += 4) {
    float4 sv[4];
    #pragma unroll
    for (int r = 0; r < 4; ++r) sv[r] = *(const float4*)&src[(r0 + r)*256 + d0];
    #pragma unroll
    for (int dd = 0; dd < 4; ++dd) {
      const float2 wv = *(const float2*)&wT[(d0 + dd)*256 + e0];
      #pragma unroll
      for (int r = 0; r < 4; ++r) {
        const float s = getc(sv[r], dd);
        a0[r] = fmaf(s, wv.x, a0[r]);
        a1[r] = fmaf(s, wv.y, a1[r]);
      }
    }
  }
}

__global__ __launch_bounds__(256) void k4_mix(
    const float* __restrict__ g, const float* __restrict__ w3,
    const float* __restrict__ bc, float* __restrict__ x, int l)
{
  __shared__ float xt[8*256];
  __shared__ float bufA[8*256];
  __shared__ float bufB[8*256];
  __shared__ float mv[8][2];
  const int t = threadIdx.x;
  const int row0 = blockIdx.x * 8;
  for (int i = t; i < 512; i += 256) {
    *(float4*)&xt[i*4]   = *(const float4*)&x[row0*256 + i*4];
    *(float4*)&bufA[i*4] = *(const float4*)&g[row0*256 + i*4];
  }
  __syncthreads();
  const int cg = t & 127, rs = t >> 7;
  const int e0 = cg * 2, r0 = rs * 4;
  const float* wl = w3 + l*3*65536;
  const float* rb2c = bc + 512  + l*256;
  const float* lngc = bc + 1024 + l*256;
  const float* lnbc = bc + 1536 + l*256;
  const float* mb1c = bc + 2048 + l*256;
  const float* mb2c = bc + 2560 + l*256;
  float a0[4], a1[4];

  tile_gemm4(bufA, wl, rb2c[e0], rb2c[e0+1], r0, e0, a0, a1);
  #pragma unroll
  for (int r = 0; r < 4; ++r) {
    const int rr = r0 + r;
    bufB[rr*256 + e0]     = xt[rr*256 + e0]     + a0[r];
    bufB[rr*256 + e0 + 1] = xt[rr*256 + e0 + 1] + a1[r];
  }
  __syncthreads();
  {
    const int row = t >> 5, part = t & 31;
    float s = 0.f, s2 = 0.f;
    for (int kk = part; kk < 256; kk += 32) {
      const float v = bufB[row*256 + kk];
      s += v; s2 = fmaf(v, v, s2);
    }
    #pragma unroll
    for (int off = 16; off; off >>= 1) {
      s  += __shfl_xor(s, off, 32);
      s2 += __shfl_xor(s2, off, 32);
    }
    if (part == 0) {
      const float mu = s * (1.f/256.f);
      mv[row][0] = mu;
      mv[row][1] = rsqrtf(fmaf(-mu, mu, s2 * (1.f/256.f)) + 1e-5f);
    }
  }
  __syncthreads();
  {
    const float g0 = lngc[e0], g1 = lngc[e0+1];
    const float c0 = lnbc[e0], c1 = lnbc[e0+1];
    #pragma unroll
    for (int r = 0; r < 4; ++r) {
      const int rr = r0 + r;
      const float m = mv[rr][0], iv = mv[rr][1];
      bufB[rr*256 + e0]     = (bufB[rr*256 + e0]     - m) * iv * g0 + c0;
      bufB[rr*256 + e0 + 1] = (bufB[rr*256 + e0 + 1] - m) * iv * g1 + c1;
    }
  }
  __syncthreads();
  tile_gemm4(bufB, wl + 65536, mb1c[e0], mb1c[e0+1], r0, e0, a0, a1);
  #pragma unroll
  for (int r = 0; r < 4; ++r) {
    const int rr = r0 + r;
    bufA[rr*256 + e0]     = gelu_e(a0[r]);
    bufA[rr*256 + e0 + 1] = gelu_e(a1[r]);
  }
  __syncthreads();
  tile_gemm4(bufA, wl + 2*65536, mb2c[e0], mb2c[e0+1], r0, e0, a0, a1);
  #pragma unroll
  for (int r = 0; r < 4; ++r) {
    const int rr = r0 + r;
    float2 o;
    o.x = xt[rr*256 + e0]     + a0[r];
    o.y = xt[rr*256 + e0 + 1] + a1[r];
    *(float2*)&x[(row0 + rr)*256 + e0] = o;
  }
}

// ---------------------------------------------------------------------------
// k5: s=sum_K x ; h=gelu(s@projT+pb) ; mu=h@muT+mb ; scale=softplus(h@spT+sb)
// ---------------------------------------------------------------------------
__global__ __launch_bounds__(256) void k5_head(
    const float* __restrict__ x, const float* __restrict__ wh,
    const float* __restrict__ bc, const int* __restrict__ flag,
    void* __restrict__ out)
{
  __shared__ float ss[256];
  __shared__ float hh[128];
  const int b = blockIdx.x, t = threadIdx.x;
  const int fl = *flag;
  float s = 0.f;
  for (int i = 0; i < 64; ++i) s += x[((b << 6) + i)*256 + t];
  ss[t] = s;
  __syncthreads();
  if (t < 128) {
    float acc = bc[3072 + t];
    const float* projT = wh;
    for (int d = 0; d < 256; ++d) acc = fmaf(ss[d], projT[d*128 + t], acc);
    hh[t] = gelu_e(acc);
  }
  __syncthreads();
  float v; int oidx;
  if (t < 128) {
    float acc = bc[3200 + t];
    const float* muT = wh + 32768;
    for (int c = 0; c < 128; ++c) acc = fmaf(hh[c], muT[c*128 + t], acc);
    v = acc; oidx = b*128 + t;
  } else {
    const int u = t - 128;
    float acc = bc[3328 + u];
    const float* spT = wh + 49152;
    for (int c = 0; c < 128; ++c) acc = fmaf(hh[c], spT[c*128 + u], acc);
    v = (acc > 20.f) ? acc : log1pf(__expf(acc));
    oidx = 4096 + b*128 + u;
  }
  if (fl) ((bf16*)out)[oidx] = __float2bfloat16(v);
  else    ((float*)out)[oidx] = v;
}

// ---------------------------------------------------------------------------
extern "C" void kernel_launch(void* const* d_in, const int* in_sizes, int n_in,
                              void* d_out, int out_size, void* d_ws, size_t ws_size,
                              hipStream_t stream)
{
  (void)in_sizes; (void)n_in; (void)out_size; (void)ws_size;
  float* ws    = (float*)d_ws;
  int*   flag  = (int*)ws;                // [16 floats reserved]
  float* x     = ws + 16;                 // 524288
  float* kqpq  = x + 524288;              // 2097152
  float* g     = kqpq + 2097152;          // 524288
  float* wf    = g + 524288;              // NL*262144 = 524288
  float* w3    = wf + 524288;             // NL*3*65536 = 393216
  float* wh    = w3 + 393216;             // 65536
  float* bc    = wh + 65536;              // 3456

  detect_kernel<<<dim3(1), dim3(256), 0, stream>>>(d_in[0], flag);
  prep_kernel<<<dim3(5902), dim3(256), 0, stream>>>(
      d_in[0], d_in[1], d_in[2], d_in[3], d_in[5], d_in[9], d_in[11],
      d_in[13], d_in[15], d_in[17],
      d_in[4], d_in[6], d_in[7], d_in[8], d_in[10], d_in[12],
      d_in[14], d_in[16], d_in[18],
      flag, x, wf, w3, wh, bc);
  for (int l = 0; l < NL; ++l) {
    k1_kqpq<<<dim3(256), dim3(256), 0, stream>>>(x, wf, bc, kqpq, l);
    k23_attn_agg<<<dim3(1024), dim3(256), 0, stream>>>(kqpq, g);
    k4_mix<<<dim3(256), dim3(256), 0, stream>>>(g, w3, bc, x, l);
  }
  k5_head<<<dim3(32), dim3(256), 0, stream>>>(x, wh, bc, flag, (void*)d_out);
}